// Round 16
// baseline (204.554 us; speedup 1.0000x reference)
//
#include <hip/hip_runtime.h>
#include <hip/hip_fp16.h>
#include <cstddef>
#include <math.h>

// Problem dims
// B=32, C=1024, T=64, D=64, F_OUT=128, S_DIM=64, N_STG=5, H_MLP=64

typedef __attribute__((ext_vector_type(8))) short bf16x8;
typedef __attribute__((ext_vector_type(4))) float f32x4;

__device__ inline unsigned f2bf(float f) {
  unsigned u = __float_as_uint(f);
  return (u + 0x7FFFu + ((u >> 16) & 1u)) >> 16;   // RTN-even
}

// workspace layout (float offsets)
#define LOGA_OFF 0u          // lam*log(A+eps) as fp16: 1024*1024 halves = 524288 floats
#define EI_OFF   524288u     // 32768
#define EJ_OFF   557056u     // 32768
#define PXG_OFF  589824u     // partial x_glob: 1024 blocks x 64 = 65536
#define ZK_OFF   655360u     // bf16 k-major Z: 2097152 floats worth

// ================= K1: mega-fused producer (R14 grid + sequential stream) ==========
// blocks 0..1023:  32 C-rows each: stream x (mean over T) -> Z GEMV ->
//                  bf16 Zk (k-major) + ei/ej + partial x_glob
// blocks 1024..2047: llogA = lam*log(A+1e-8) packed to fp16 (one row/block;
//                  light blocks dispatched last -> they fill the x-block tail)
// Stream: wave w owns rows w*8..w*8+7 SEQUENTIALLY — one contiguous 16KB
// sweep at a time (1 DRAM stream/wave, 4/block); all shfl reductions deferred
// to the end. Per-row summation order identical to R14 -> bit-identical xr.
__global__ __launch_bounds__(256) void k_fuse1(
    const float4* __restrict__ X4, const float* __restrict__ A,
    const float* __restrict__ lam, const float* __restrict__ W,
    const float* __restrict__ bproj, const float* __restrict__ att,
    uint4* __restrict__ Zk, float* __restrict__ ei, float* __restrict__ ej,
    float4* __restrict__ pXG4, __half* __restrict__ llogA) {
  int tid = threadIdx.x;
  int bk = blockIdx.x;
  if (bk >= 1024) {
    float l = lam[0];
    int row = bk - 1024;
    const float4* Arow = (const float4*)(A + (size_t)row * 1024);
    float4 a = Arow[tid];
    __half2 h0 = __floats2half2_rn(l * __logf(a.x + 1e-8f),
                                   l * __logf(a.y + 1e-8f));
    __half2 h1 = __floats2half2_rn(l * __logf(a.z + 1e-8f),
                                   l * __logf(a.w + 1e-8f));
    union { __half2 h[2]; uint2 u; } pk;
    pk.h[0] = h0; pk.h[1] = h1;
    ((uint2*)llogA)[(size_t)row * 256 + tid] = pk.u;
    return;
  }
  __shared__ float Wl[64 * 129];     // W transposed [d][f]; reused as Zl[32][130]
  __shared__ float4 xr4[32 * 16];    // x_red tile [row][dq]
  int rb = bk * 32;                  // flat row base (b*1024 + c0)

  // stage W transposed (L2-hot after first blocks)
#pragma unroll
  for (int k = 0; k < 32; ++k) {
    int g = k * 256 + tid;           // g = f*64 + d
    Wl[(g & 63) * 129 + (g >> 6)] = W[g];
  }

  // stream x: sequential per-wave contiguous row sweeps, deferred reductions.
  // lane l reads offset l of each 1KB step (t = s*4 + (l>>4), dq = l&15).
  {
    int w = tid >> 6, l = tid & 63;
    int tg = l >> 4, dq = l & 15;
    int r0 = w * 8;
    const float4* base = X4 + ((size_t)(rb + r0)) * 1024 + l;
    float4 ar[8];
#pragma unroll
    for (int r = 0; r < 8; ++r) {
      const float4* bp = base + (size_t)r * 1024;
      float4 a = make_float4(0.f, 0.f, 0.f, 0.f);
#pragma unroll
      for (int s = 0; s < 16; ++s) {
        float4 v = bp[s * 64];
        a.x += v.x; a.y += v.y; a.z += v.z; a.w += v.w;
      }
      ar[r] = a;
    }
    const float inv = 1.0f / 64.0f;
#pragma unroll
    for (int r = 0; r < 8; ++r) {
      float4 a = ar[r];
      a.x += __shfl_xor(a.x, 16); a.y += __shfl_xor(a.y, 16);
      a.z += __shfl_xor(a.z, 16); a.w += __shfl_xor(a.w, 16);
      a.x += __shfl_xor(a.x, 32); a.y += __shfl_xor(a.y, 32);
      a.z += __shfl_xor(a.z, 32); a.w += __shfl_xor(a.w, 32);
      if (tg == 0) {
        a.x *= inv; a.y *= inv; a.z *= inv; a.w *= inv;
        xr4[(r0 + r) * 16 + dq] = a;
      }
    }
  }
  __syncthreads();

  // partial x_glob: sum of this block's 32 xr rows
  if (tid < 16) {
    float4 p = make_float4(0.f, 0.f, 0.f, 0.f);
#pragma unroll
    for (int r = 0; r < 32; ++r) {
      float4 v = xr4[r * 16 + tid];
      p.x += v.x; p.y += v.y; p.z += v.z; p.w += v.w;
    }
    pXG4[bk * 16 + tid] = p;
  }

  // GEMV: Z[row][f] = b[f] + xr[row,:] . W[f,:]
  int f = tid & 127, rg = tid >> 7;
  float wreg[64];
#pragma unroll
  for (int d = 0; d < 64; ++d) wreg[d] = Wl[d * 129 + f];
  float bias = bproj[f];
  float acc[16];
#pragma unroll
  for (int r = 0; r < 16; ++r) acc[r] = bias;
#pragma unroll
  for (int r = 0; r < 16; ++r) {
    int row = rg * 16 + r;
#pragma unroll
    for (int dq = 0; dq < 16; ++dq) {
      float4 xv = xr4[row * 16 + dq];
      acc[r] = fmaf(wreg[dq * 4 + 0], xv.x, acc[r]);
      acc[r] = fmaf(wreg[dq * 4 + 1], xv.y, acc[r]);
      acc[r] = fmaf(wreg[dq * 4 + 2], xv.z, acc[r]);
      acc[r] = fmaf(wreg[dq * 4 + 3], xv.w, acc[r]);
    }
  }
  // bf16 k-major chunks: Zk[b][c/8][f][c&7]
  int b = rb >> 10;
  int cbase = (rb & 1023) + rg * 16;
#pragma unroll
  for (int k2 = 0; k2 < 2; ++k2) {
    unsigned w0 = f2bf(acc[k2 * 8 + 0]) | (f2bf(acc[k2 * 8 + 1]) << 16);
    unsigned w1 = f2bf(acc[k2 * 8 + 2]) | (f2bf(acc[k2 * 8 + 3]) << 16);
    unsigned w2 = f2bf(acc[k2 * 8 + 4]) | (f2bf(acc[k2 * 8 + 5]) << 16);
    unsigned w3 = f2bf(acc[k2 * 8 + 6]) | (f2bf(acc[k2 * 8 + 7]) << 16);
    size_t chunk = ((size_t)b * 128 + ((cbase >> 3) + k2)) * 128 + f;
    Zk[chunk] = make_uint4(w0, w1, w2, w3);
  }
  // ei/ej tail: stage fp32 Z tile into LDS (reuse Wl), reduce
  __syncthreads();                   // all Wl/xr4 reads done
  float* Zl = Wl;                    // [32][130]
#pragma unroll
  for (int r = 0; r < 16; ++r)
    Zl[(rg * 16 + r) * 130 + f] = acc[r];
  __syncthreads();
  int row = tid >> 3, g = tid & 7;   // 32 rows x 8 groups of 16 f
  float si = 0.f, sj = 0.f;
#pragma unroll
  for (int u = 0; u < 16; ++u) {
    float z = Zl[row * 130 + g * 16 + u];
    si = fmaf(z, att[g * 16 + u], si);
    sj = fmaf(z, att[128 + g * 16 + u], sj);
  }
  si += __shfl_xor(si, 1); sj += __shfl_xor(sj, 1);
  si += __shfl_xor(si, 2); sj += __shfl_xor(sj, 2);
  si += __shfl_xor(si, 4); sj += __shfl_xor(sj, 4);
  if (g == 0) { ei[rb + row] = si; ej[rb + row] = sj; }
}

// ================= K2: flash softmax @ Z via MFMA (R12-exact) =================
__global__ __launch_bounds__(64) void k_main(const uint4* __restrict__ Zk,
    const __half* __restrict__ llogA, const float* __restrict__ ei,
    const float* __restrict__ ej, const float* __restrict__ pXG,
    const float* __restrict__ Ws1, const float* __restrict__ bs1,
    const float* __restrict__ Ws2, const float* __restrict__ bs2,
    const float* __restrict__ Wc1, const float* __restrict__ bc1,
    const float* __restrict__ Wc2, const float* __restrict__ bc2,
    const float* __restrict__ att,
    float* __restrict__ hout, float* __restrict__ sout) {
  int bid = blockIdx.x;
  int b = ((bid & 7) << 2) | ((bid >> 3) & 3);
  int rowgrp = bid >> 5;               // 0..63
  int i0 = rowgrp * 16;
  int lane = threadIdx.x;
  int lg = lane >> 4, ln = lane & 15;

  // ---- pre-phase: x_glob -> s -> c -> ec (shfl-based, wave-local) ----
  float ecb;
  {
    float xg = 0.f;
    const float* pb = pXG + (size_t)b * 32 * 64;
#pragma unroll 8
    for (int p = 0; p < 32; ++p) xg += pb[p * 64 + lane];
    xg *= (1.0f / 1024.0f);
    const float* w1 = Ws1 + lane * 64;
    float h = bs1[lane];
#pragma unroll 16
    for (int d = 0; d < 64; ++d) h = fmaf(__shfl(xg, d), w1[d], h);
    h = fmaxf(h, 0.f);
    int ln5 = lane < 5 ? lane : 4;
    const float* w2 = Ws2 + ln5 * 64;
    float l = bs2[ln5];
#pragma unroll 16
    for (int k = 0; k < 64; ++k) l = fmaf(__shfl(h, k), w2[k], l);
    float s0 = __shfl(l, 0), s1 = __shfl(l, 1), s2 = __shfl(l, 2),
          s3 = __shfl(l, 3), s4 = __shfl(l, 4);
    float m = fmaxf(fmaxf(fmaxf(s0, s1), fmaxf(s2, s3)), s4);
    float e0 = __expf(s0 - m), e1 = __expf(s1 - m), e2 = __expf(s2 - m),
          e3 = __expf(s3 - m), e4 = __expf(s4 - m);
    float inv = 1.0f / (e0 + e1 + e2 + e3 + e4);
    s0 = e0 * inv; s1 = e1 * inv; s2 = e2 * inv; s3 = e3 * inv; s4 = e4 * inv;
    if (rowgrp == 0 && lane == 0) {
      sout[b * 5 + 0] = s0; sout[b * 5 + 1] = s1; sout[b * 5 + 2] = s2;
      sout[b * 5 + 3] = s3; sout[b * 5 + 4] = s4;
    }
    const float* wc1 = Wc1 + lane * 5;
    float cv = bc1[lane];
    cv = fmaf(s0, wc1[0], cv); cv = fmaf(s1, wc1[1], cv);
    cv = fmaf(s2, wc1[2], cv); cv = fmaf(s3, wc1[3], cv);
    cv = fmaf(s4, wc1[4], cv);
    cv = fmaxf(cv, 0.f);
    const float* wc2 = Wc2 + lane * 64;
    float c2 = bc2[lane];
#pragma unroll 16
    for (int k = 0; k < 64; ++k) c2 = fmaf(__shfl(cv, k), wc2[k], c2);
    float v = c2 * att[256 + lane];
#pragma unroll
    for (int o = 32; o; o >>= 1) v += __shfl_xor(v, o);
    ecb = v;
  }

  // ---- flash loop ----
  int i_gl = i0 + ln;
  float eir = ei[b * 1024 + i_gl];
  const uint4*  lrowH = (const uint4*)(llogA + (size_t)i_gl * 1024); // 8 halves/chunk
  const float4* ejr4  = (const float4*)(ej + b * 1024);
  const uint4*  ZkB   = Zk + (size_t)b * 128 * 128;

  float m_run = -1e30f, s_run = 0.0f;
  f32x4 acc[8];
#pragma unroll
  for (int q = 0; q < 8; ++q) { f32x4 z = {0.f, 0.f, 0.f, 0.f}; acc[q] = z; }

  for (int jt = 0; jt < 16; ++jt) {
    int j0 = jt * 64;
    uint4 bz[2][8];
#pragma unroll
    for (int ks = 0; ks < 2; ++ks)
#pragma unroll
      for (int fb = 0; fb < 8; ++fb)
        bz[ks][fb] = ZkB[(size_t)((j0 >> 3) + ks * 4 + lg) * 128 + fb * 16 + ln];
    float tv[16];
    float tm = -1e30f;
#pragma unroll
    for (int ks = 0; ks < 2; ++ks) {
      int jb = (j0 + ks * 32 + lg * 8) >> 2;      // float4 index (ej)
      float4 e0 = ejr4[jb], e1 = ejr4[jb + 1];
      union { uint4 u; __half2 h[4]; } lu;
      lu.u = lrowH[jb >> 1];                      // 8 halves = same 8 j's
      float2 f0 = __half22float2(lu.h[0]);
      float2 f1 = __half22float2(lu.h[1]);
      float2 f2 = __half22float2(lu.h[2]);
      float2 f3 = __half22float2(lu.h[3]);
      float eq[8] = {e0.x, e0.y, e0.z, e0.w, e1.x, e1.y, e1.z, e1.w};
      float lq[8] = {f0.x, f0.y, f1.x, f1.y, f2.x, f2.y, f3.x, f3.y};
#pragma unroll
      for (int u = 0; u < 8; ++u) {
        float t = eir + eq[u] + ecb;
        t = t > 0.0f ? t : 0.2f * t;          // leaky_relu(0.2)
        t += lq[u];                            // + lam*log(A+eps) (fp16)
        tv[ks * 8 + u] = t;
        tm = fmaxf(tm, t);
      }
    }
    tm = fmaxf(tm, __shfl_xor(tm, 16));
    tm = fmaxf(tm, __shfl_xor(tm, 32));
    float newm = fmaxf(m_run, tm);
    float scale = __expf(m_run - newm);
    float ts = 0.0f;
    unsigned pw[8];
#pragma unroll
    for (int q = 0; q < 8; ++q) {
      float p0 = __expf(tv[2 * q] - newm);
      float p1 = __expf(tv[2 * q + 1] - newm);
      ts += p0 + p1;
      pw[q] = f2bf(p0) | (f2bf(p1) << 16);
    }
    ts += __shfl_xor(ts, 16);
    ts += __shfl_xor(ts, 32);
    s_run = s_run * scale + ts;
    m_run = newm;
#pragma unroll
    for (int q = 0; q < 8; ++q) acc[q] *= scale;
    union { unsigned u[4]; bf16x8 v; } c0, c1;
#pragma unroll
    for (int q = 0; q < 4; ++q) { c0.u[q] = pw[q]; c1.u[q] = pw[4 + q]; }
#pragma unroll
    for (int fb = 0; fb < 8; ++fb)
      acc[fb] = __builtin_amdgcn_mfma_f32_16x16x32_bf16(c0.v, *(bf16x8*)&bz[0][fb], acc[fb], 0, 0, 0);
#pragma unroll
    for (int fb = 0; fb < 8; ++fb)
      acc[fb] = __builtin_amdgcn_mfma_f32_16x16x32_bf16(c1.v, *(bf16x8*)&bz[1][fb], acc[fb], 0, 0, 0);
  }

  // epilogue: normalize by D-row 1/s, write out
  float invs = 1.0f / s_run;
  float inv_m[4];
#pragma unroll
  for (int r = 0; r < 4; ++r) inv_m[r] = __shfl(invs, lg * 4 + r);
  float* hb = hout + ((size_t)b * 1024 + i0 + lg * 4) * 128 + ln;
#pragma unroll
  for (int fb = 0; fb < 8; ++fb) {
#pragma unroll
    for (int r = 0; r < 4; ++r)
      hb[(size_t)r * 128 + fb * 16] = acc[fb][r] * inv_m[r];
  }
}

extern "C" void kernel_launch(void* const* d_in, const int* in_sizes, int n_in,
                              void* d_out, int out_size, void* d_ws, size_t ws_size,
                              hipStream_t stream) {
  const float* x     = (const float*)d_in[0];
  const float* Ainit = (const float*)d_in[1];
  const float* Wproj = (const float*)d_in[2];
  const float* bproj = (const float*)d_in[3];
  const float* Ws1   = (const float*)d_in[4];
  const float* bs1   = (const float*)d_in[5];
  const float* Ws2   = (const float*)d_in[6];
  const float* bs2   = (const float*)d_in[7];
  const float* Wc1   = (const float*)d_in[8];
  const float* bc1   = (const float*)d_in[9];
  const float* Wc2   = (const float*)d_in[10];
  const float* bc2   = (const float*)d_in[11];
  const float* att   = (const float*)d_in[12];
  const float* lam   = (const float*)d_in[13];

  float* ws    = (float*)d_ws;
  __half* llogA = (__half*)(ws + LOGA_OFF);
  float* ei    = ws + EI_OFF;
  float* ej    = ws + EJ_OFF;
  float* pXG   = ws + PXG_OFF;
  uint4* Zk    = (uint4*)(ws + ZK_OFF);

  float* hout = (float*)d_out;                  // (32,1024,128)
  float* sout = hout + (size_t)32 * 1024 * 128; // (32,5)

  hipLaunchKernelGGL(k_fuse1, dim3(2048), dim3(256), 0, stream,
                     (const float4*)x, Ainit, lam, Wproj, bproj, att,
                     Zk, ei, ej, (float4*)pXG, llogA);
  hipLaunchKernelGGL(k_main,  dim3(2048), dim3(64),  0, stream,
                     Zk, llogA, ei, ej, pXG,
                     Ws1, bs1, Ws2, bs2, Wc1, bc1, Wc2, bc2, att,
                     hout, sout);
}

// Round 17
// 165.044 us; speedup vs baseline: 1.2394x; 1.2394x over previous
//
#include <hip/hip_runtime.h>
#include <hip/hip_fp16.h>
#include <cstddef>
#include <math.h>

// Problem dims
// B=32, C=1024, T=64, D=64, F_OUT=128, S_DIM=64, N_STG=5, H_MLP=64

typedef __attribute__((ext_vector_type(8))) short bf16x8;
typedef __attribute__((ext_vector_type(4))) float f32x4;

__device__ inline unsigned f2bf(float f) {
  unsigned u = __float_as_uint(f);
  return (u + 0x7FFFu + ((u >> 16) & 1u)) >> 16;   // RTN-even
}

// workspace layout (float offsets)
#define LOGA_OFF 0u          // lam*log(A+eps) as fp16: 1024*1024 halves = 524288 floats
#define EI_OFF   524288u     // 32768
#define EJ_OFF   557056u     // 32768
#define PXG_OFF  589824u     // partial x_glob: 1024 blocks x 64 = 65536
#define ZK_OFF   655360u     // bf16 k-major Z: 2097152 floats worth

// ================= K1: mega-fused producer (R14 + quad streams) =================
// blocks 0..1023:  32 C-rows each: stream x (mean over T) -> Z GEMV ->
//                  bf16 Zk (k-major) + ei/ej + partial x_glob
// blocks 1024..2047: llogA = lam*log(A+1e-8) packed to fp16 (one row/block)
// Stream: wave w owns rows w*8..w*8+7 as 2 QUADS of 4 concurrent contiguous
// 16KB sweeps (4 streams/wave; R14 had 2, R16's 1 and R15's 8 both lost).
// Per-row summation order identical to R14 -> bit-identical xr.
__global__ __launch_bounds__(256) void k_fuse1(
    const float4* __restrict__ X4, const float* __restrict__ A,
    const float* __restrict__ lam, const float* __restrict__ W,
    const float* __restrict__ bproj, const float* __restrict__ att,
    uint4* __restrict__ Zk, float* __restrict__ ei, float* __restrict__ ej,
    float4* __restrict__ pXG4, __half* __restrict__ llogA) {
  int tid = threadIdx.x;
  int bk = blockIdx.x;
  if (bk >= 1024) {
    float l = lam[0];
    int row = bk - 1024;
    const float4* Arow = (const float4*)(A + (size_t)row * 1024);
    float4 a = Arow[tid];
    __half2 h0 = __floats2half2_rn(l * __logf(a.x + 1e-8f),
                                   l * __logf(a.y + 1e-8f));
    __half2 h1 = __floats2half2_rn(l * __logf(a.z + 1e-8f),
                                   l * __logf(a.w + 1e-8f));
    union { __half2 h[2]; uint2 u; } pk;
    pk.h[0] = h0; pk.h[1] = h1;
    ((uint2*)llogA)[(size_t)row * 256 + tid] = pk.u;
    return;
  }
  __shared__ float Wl[64 * 129];     // W transposed [d][f]; reused as Zl[32][130]
  __shared__ float4 xr4[32 * 16];    // x_red tile [row][dq]
  int rb = bk * 32;                  // flat row base (b*1024 + c0)

  // stage W transposed (L2-hot after first blocks)
#pragma unroll
  for (int k = 0; k < 32; ++k) {
    int g = k * 256 + tid;           // g = f*64 + d
    Wl[(g & 63) * 129 + (g >> 6)] = W[g];
  }

  // stream x: 2 quads of 4 concurrent contiguous row sweeps per wave.
  // lane l reads offset l of each 1KB step (t = s*4 + (l>>4), dq = l&15).
  {
    int w = tid >> 6, l = tid & 63;
    int tg = l >> 4, dq = l & 15;
#pragma unroll
    for (int p = 0; p < 2; ++p) {
      int rA = w * 8 + p * 4;
      const float4* b0 = X4 + ((size_t)(rb + rA + 0)) * 1024 + l;
      const float4* b1 = X4 + ((size_t)(rb + rA + 1)) * 1024 + l;
      const float4* b2 = X4 + ((size_t)(rb + rA + 2)) * 1024 + l;
      const float4* b3 = X4 + ((size_t)(rb + rA + 3)) * 1024 + l;
      float4 a0 = make_float4(0.f, 0.f, 0.f, 0.f);
      float4 a1 = a0, a2 = a0, a3 = a0;
#pragma unroll
      for (int s = 0; s < 16; ++s) {
        int o = s * 64;
        float4 v0 = b0[o];
        float4 v1 = b1[o];
        float4 v2 = b2[o];
        float4 v3 = b3[o];
        a0.x += v0.x; a0.y += v0.y; a0.z += v0.z; a0.w += v0.w;
        a1.x += v1.x; a1.y += v1.y; a1.z += v1.z; a1.w += v1.w;
        a2.x += v2.x; a2.y += v2.y; a2.z += v2.z; a2.w += v2.w;
        a3.x += v3.x; a3.y += v3.y; a3.z += v3.z; a3.w += v3.w;
      }
      float4 ar[4] = {a0, a1, a2, a3};
      const float inv = 1.0f / 64.0f;
#pragma unroll
      for (int r = 0; r < 4; ++r) {
        float4 a = ar[r];
        a.x += __shfl_xor(a.x, 16); a.y += __shfl_xor(a.y, 16);
        a.z += __shfl_xor(a.z, 16); a.w += __shfl_xor(a.w, 16);
        a.x += __shfl_xor(a.x, 32); a.y += __shfl_xor(a.y, 32);
        a.z += __shfl_xor(a.z, 32); a.w += __shfl_xor(a.w, 32);
        if (tg == 0) {
          a.x *= inv; a.y *= inv; a.z *= inv; a.w *= inv;
          xr4[(rA + r) * 16 + dq] = a;
        }
      }
    }
  }
  __syncthreads();

  // partial x_glob: sum of this block's 32 xr rows
  if (tid < 16) {
    float4 p = make_float4(0.f, 0.f, 0.f, 0.f);
#pragma unroll
    for (int r = 0; r < 32; ++r) {
      float4 v = xr4[r * 16 + tid];
      p.x += v.x; p.y += v.y; p.z += v.z; p.w += v.w;
    }
    pXG4[bk * 16 + tid] = p;
  }

  // GEMV: Z[row][f] = b[f] + xr[row,:] . W[f,:]
  int f = tid & 127, rg = tid >> 7;
  float wreg[64];
#pragma unroll
  for (int d = 0; d < 64; ++d) wreg[d] = Wl[d * 129 + f];
  float bias = bproj[f];
  float acc[16];
#pragma unroll
  for (int r = 0; r < 16; ++r) acc[r] = bias;
#pragma unroll
  for (int r = 0; r < 16; ++r) {
    int row = rg * 16 + r;
#pragma unroll
    for (int dq = 0; dq < 16; ++dq) {
      float4 xv = xr4[row * 16 + dq];
      acc[r] = fmaf(wreg[dq * 4 + 0], xv.x, acc[r]);
      acc[r] = fmaf(wreg[dq * 4 + 1], xv.y, acc[r]);
      acc[r] = fmaf(wreg[dq * 4 + 2], xv.z, acc[r]);
      acc[r] = fmaf(wreg[dq * 4 + 3], xv.w, acc[r]);
    }
  }
  // bf16 k-major chunks: Zk[b][c/8][f][c&7]
  int b = rb >> 10;
  int cbase = (rb & 1023) + rg * 16;
#pragma unroll
  for (int k2 = 0; k2 < 2; ++k2) {
    unsigned w0 = f2bf(acc[k2 * 8 + 0]) | (f2bf(acc[k2 * 8 + 1]) << 16);
    unsigned w1 = f2bf(acc[k2 * 8 + 2]) | (f2bf(acc[k2 * 8 + 3]) << 16);
    unsigned w2 = f2bf(acc[k2 * 8 + 4]) | (f2bf(acc[k2 * 8 + 5]) << 16);
    unsigned w3 = f2bf(acc[k2 * 8 + 6]) | (f2bf(acc[k2 * 8 + 7]) << 16);
    size_t chunk = ((size_t)b * 128 + ((cbase >> 3) + k2)) * 128 + f;
    Zk[chunk] = make_uint4(w0, w1, w2, w3);
  }
  // ei/ej tail: stage fp32 Z tile into LDS (reuse Wl), reduce
  __syncthreads();                   // all Wl/xr4 reads done
  float* Zl = Wl;                    // [32][130]
#pragma unroll
  for (int r = 0; r < 16; ++r)
    Zl[(rg * 16 + r) * 130 + f] = acc[r];
  __syncthreads();
  int row = tid >> 3, g = tid & 7;   // 32 rows x 8 groups of 16 f
  float si = 0.f, sj = 0.f;
#pragma unroll
  for (int u = 0; u < 16; ++u) {
    float z = Zl[row * 130 + g * 16 + u];
    si = fmaf(z, att[g * 16 + u], si);
    sj = fmaf(z, att[128 + g * 16 + u], sj);
  }
  si += __shfl_xor(si, 1); sj += __shfl_xor(sj, 1);
  si += __shfl_xor(si, 2); sj += __shfl_xor(sj, 2);
  si += __shfl_xor(si, 4); sj += __shfl_xor(sj, 4);
  if (g == 0) { ei[rb + row] = si; ej[rb + row] = sj; }
}

// ================= K2: flash softmax @ Z via MFMA (R12-exact) =================
__global__ __launch_bounds__(64) void k_main(const uint4* __restrict__ Zk,
    const __half* __restrict__ llogA, const float* __restrict__ ei,
    const float* __restrict__ ej, const float* __restrict__ pXG,
    const float* __restrict__ Ws1, const float* __restrict__ bs1,
    const float* __restrict__ Ws2, const float* __restrict__ bs2,
    const float* __restrict__ Wc1, const float* __restrict__ bc1,
    const float* __restrict__ Wc2, const float* __restrict__ bc2,
    const float* __restrict__ att,
    float* __restrict__ hout, float* __restrict__ sout) {
  int bid = blockIdx.x;
  int b = ((bid & 7) << 2) | ((bid >> 3) & 3);
  int rowgrp = bid >> 5;               // 0..63
  int i0 = rowgrp * 16;
  int lane = threadIdx.x;
  int lg = lane >> 4, ln = lane & 15;

  // ---- pre-phase: x_glob -> s -> c -> ec (shfl-based, wave-local) ----
  float ecb;
  {
    float xg = 0.f;
    const float* pb = pXG + (size_t)b * 32 * 64;
#pragma unroll 8
    for (int p = 0; p < 32; ++p) xg += pb[p * 64 + lane];
    xg *= (1.0f / 1024.0f);
    const float* w1 = Ws1 + lane * 64;
    float h = bs1[lane];
#pragma unroll 16
    for (int d = 0; d < 64; ++d) h = fmaf(__shfl(xg, d), w1[d], h);
    h = fmaxf(h, 0.f);
    int ln5 = lane < 5 ? lane : 4;
    const float* w2 = Ws2 + ln5 * 64;
    float l = bs2[ln5];
#pragma unroll 16
    for (int k = 0; k < 64; ++k) l = fmaf(__shfl(h, k), w2[k], l);
    float s0 = __shfl(l, 0), s1 = __shfl(l, 1), s2 = __shfl(l, 2),
          s3 = __shfl(l, 3), s4 = __shfl(l, 4);
    float m = fmaxf(fmaxf(fmaxf(s0, s1), fmaxf(s2, s3)), s4);
    float e0 = __expf(s0 - m), e1 = __expf(s1 - m), e2 = __expf(s2 - m),
          e3 = __expf(s3 - m), e4 = __expf(s4 - m);
    float inv = 1.0f / (e0 + e1 + e2 + e3 + e4);
    s0 = e0 * inv; s1 = e1 * inv; s2 = e2 * inv; s3 = e3 * inv; s4 = e4 * inv;
    if (rowgrp == 0 && lane == 0) {
      sout[b * 5 + 0] = s0; sout[b * 5 + 1] = s1; sout[b * 5 + 2] = s2;
      sout[b * 5 + 3] = s3; sout[b * 5 + 4] = s4;
    }
    const float* wc1 = Wc1 + lane * 5;
    float cv = bc1[lane];
    cv = fmaf(s0, wc1[0], cv); cv = fmaf(s1, wc1[1], cv);
    cv = fmaf(s2, wc1[2], cv); cv = fmaf(s3, wc1[3], cv);
    cv = fmaf(s4, wc1[4], cv);
    cv = fmaxf(cv, 0.f);
    const float* wc2 = Wc2 + lane * 64;
    float c2 = bc2[lane];
#pragma unroll 16
    for (int k = 0; k < 64; ++k) c2 = fmaf(__shfl(cv, k), wc2[k], c2);
    float v = c2 * att[256 + lane];
#pragma unroll
    for (int o = 32; o; o >>= 1) v += __shfl_xor(v, o);
    ecb = v;
  }

  // ---- flash loop ----
  int i_gl = i0 + ln;
  float eir = ei[b * 1024 + i_gl];
  const uint4*  lrowH = (const uint4*)(llogA + (size_t)i_gl * 1024); // 8 halves/chunk
  const float4* ejr4  = (const float4*)(ej + b * 1024);
  const uint4*  ZkB   = Zk + (size_t)b * 128 * 128;

  float m_run = -1e30f, s_run = 0.0f;
  f32x4 acc[8];
#pragma unroll
  for (int q = 0; q < 8; ++q) { f32x4 z = {0.f, 0.f, 0.f, 0.f}; acc[q] = z; }

  for (int jt = 0; jt < 16; ++jt) {
    int j0 = jt * 64;
    uint4 bz[2][8];
#pragma unroll
    for (int ks = 0; ks < 2; ++ks)
#pragma unroll
      for (int fb = 0; fb < 8; ++fb)
        bz[ks][fb] = ZkB[(size_t)((j0 >> 3) + ks * 4 + lg) * 128 + fb * 16 + ln];
    float tv[16];
    float tm = -1e30f;
#pragma unroll
    for (int ks = 0; ks < 2; ++ks) {
      int jb = (j0 + ks * 32 + lg * 8) >> 2;      // float4 index (ej)
      float4 e0 = ejr4[jb], e1 = ejr4[jb + 1];
      union { uint4 u; __half2 h[4]; } lu;
      lu.u = lrowH[jb >> 1];                      // 8 halves = same 8 j's
      float2 f0 = __half22float2(lu.h[0]);
      float2 f1 = __half22float2(lu.h[1]);
      float2 f2 = __half22float2(lu.h[2]);
      float2 f3 = __half22float2(lu.h[3]);
      float eq[8] = {e0.x, e0.y, e0.z, e0.w, e1.x, e1.y, e1.z, e1.w};
      float lq[8] = {f0.x, f0.y, f1.x, f1.y, f2.x, f2.y, f3.x, f3.y};
#pragma unroll
      for (int u = 0; u < 8; ++u) {
        float t = eir + eq[u] + ecb;
        t = t > 0.0f ? t : 0.2f * t;          // leaky_relu(0.2)
        t += lq[u];                            // + lam*log(A+eps) (fp16)
        tv[ks * 8 + u] = t;
        tm = fmaxf(tm, t);
      }
    }
    tm = fmaxf(tm, __shfl_xor(tm, 16));
    tm = fmaxf(tm, __shfl_xor(tm, 32));
    float newm = fmaxf(m_run, tm);
    float scale = __expf(m_run - newm);
    float ts = 0.0f;
    unsigned pw[8];
#pragma unroll
    for (int q = 0; q < 8; ++q) {
      float p0 = __expf(tv[2 * q] - newm);
      float p1 = __expf(tv[2 * q + 1] - newm);
      ts += p0 + p1;
      pw[q] = f2bf(p0) | (f2bf(p1) << 16);
    }
    ts += __shfl_xor(ts, 16);
    ts += __shfl_xor(ts, 32);
    s_run = s_run * scale + ts;
    m_run = newm;
#pragma unroll
    for (int q = 0; q < 8; ++q) acc[q] *= scale;
    union { unsigned u[4]; bf16x8 v; } c0, c1;
#pragma unroll
    for (int q = 0; q < 4; ++q) { c0.u[q] = pw[q]; c1.u[q] = pw[4 + q]; }
#pragma unroll
    for (int fb = 0; fb < 8; ++fb)
      acc[fb] = __builtin_amdgcn_mfma_f32_16x16x32_bf16(c0.v, *(bf16x8*)&bz[0][fb], acc[fb], 0, 0, 0);
#pragma unroll
    for (int fb = 0; fb < 8; ++fb)
      acc[fb] = __builtin_amdgcn_mfma_f32_16x16x32_bf16(c1.v, *(bf16x8*)&bz[1][fb], acc[fb], 0, 0, 0);
  }

  // epilogue: normalize by D-row 1/s, write out
  float invs = 1.0f / s_run;
  float inv_m[4];
#pragma unroll
  for (int r = 0; r < 4; ++r) inv_m[r] = __shfl(invs, lg * 4 + r);
  float* hb = hout + ((size_t)b * 1024 + i0 + lg * 4) * 128 + ln;
#pragma unroll
  for (int fb = 0; fb < 8; ++fb) {
#pragma unroll
    for (int r = 0; r < 4; ++r)
      hb[(size_t)r * 128 + fb * 16] = acc[fb][r] * inv_m[r];
  }
}

extern "C" void kernel_launch(void* const* d_in, const int* in_sizes, int n_in,
                              void* d_out, int out_size, void* d_ws, size_t ws_size,
                              hipStream_t stream) {
  const float* x     = (const float*)d_in[0];
  const float* Ainit = (const float*)d_in[1];
  const float* Wproj = (const float*)d_in[2];
  const float* bproj = (const float*)d_in[3];
  const float* Ws1   = (const float*)d_in[4];
  const float* bs1   = (const float*)d_in[5];
  const float* Ws2   = (const float*)d_in[6];
  const float* bs2   = (const float*)d_in[7];
  const float* Wc1   = (const float*)d_in[8];
  const float* bc1   = (const float*)d_in[9];
  const float* Wc2   = (const float*)d_in[10];
  const float* bc2   = (const float*)d_in[11];
  const float* att   = (const float*)d_in[12];
  const float* lam   = (const float*)d_in[13];

  float* ws    = (float*)d_ws;
  __half* llogA = (__half*)(ws + LOGA_OFF);
  float* ei    = ws + EI_OFF;
  float* ej    = ws + EJ_OFF;
  float* pXG   = ws + PXG_OFF;
  uint4* Zk    = (uint4*)(ws + ZK_OFF);

  float* hout = (float*)d_out;                  // (32,1024,128)
  float* sout = hout + (size_t)32 * 1024 * 128; // (32,5)

  hipLaunchKernelGGL(k_fuse1, dim3(2048), dim3(256), 0, stream,
                     (const float4*)x, Ainit, lam, Wproj, bproj, att,
                     Zk, ei, ej, (float4*)pXG, llogA);
  hipLaunchKernelGGL(k_main,  dim3(2048), dim3(64),  0, stream,
                     Zk, llogA, ei, ej, pXG,
                     Ws1, bs1, Ws2, bs2, Wc1, bc1, Wc2, bc2, att,
                     hout, sout);
}

// Round 18
// 149.216 us; speedup vs baseline: 1.3709x; 1.1061x over previous
//
#include <hip/hip_runtime.h>
#include <hip/hip_fp16.h>
#include <cstddef>
#include <math.h>

// Problem dims
// B=32, C=1024, T=64, D=64, F_OUT=128, S_DIM=64, N_STG=5, H_MLP=64

typedef __attribute__((ext_vector_type(8))) short bf16x8;
typedef __attribute__((ext_vector_type(4))) float f32x4;

__device__ inline unsigned f2bf(float f) {
  unsigned u = __float_as_uint(f);
  return (u + 0x7FFFu + ((u >> 16) & 1u)) >> 16;   // RTN-even
}

// workspace layout (float offsets)
#define LOGA_OFF 0u          // lam*log(A+eps) as fp16: 1024*1024 halves = 524288 floats
#define EI_OFF   524288u     // 32768
#define EJ_OFF   557056u     // 32768
#define PXG_OFF  589824u     // partial x_glob: 1024 blocks x 64 = 65536
#define ZK_OFF   655360u     // bf16 k-major Z: 2097152 floats worth

// ================= K1: mega-fused producer (R14-exact + NT x-loads) =================
// blocks 0..1023:  32 C-rows each: stream x (mean over T) -> Z GEMV ->
//                  bf16 Zk (k-major) + ei/ej + partial x_glob
// blocks 1024..2047: llogA = lam*log(A+1e-8) packed to fp16 (one row/block)
// Stream: R14's optimal pair form (wave w owns 8 rows as 4 pairs of
// interleaved contiguous 16KB sweeps; dose-response 1/2/4/8 streams ->
// 204/161/165/182). NEW: x loads are NONTEMPORAL (x is read-once; keep it
// out of L1/L2/L3 so the caches serve Wl/Zk/llogA instead).
__global__ __launch_bounds__(256) void k_fuse1(
    const float4* __restrict__ X4, const float* __restrict__ A,
    const float* __restrict__ lam, const float* __restrict__ W,
    const float* __restrict__ bproj, const float* __restrict__ att,
    uint4* __restrict__ Zk, float* __restrict__ ei, float* __restrict__ ej,
    float4* __restrict__ pXG4, __half* __restrict__ llogA) {
  int tid = threadIdx.x;
  int bk = blockIdx.x;
  if (bk >= 1024) {
    float l = lam[0];
    int row = bk - 1024;
    const float4* Arow = (const float4*)(A + (size_t)row * 1024);
    float4 a = Arow[tid];
    __half2 h0 = __floats2half2_rn(l * __logf(a.x + 1e-8f),
                                   l * __logf(a.y + 1e-8f));
    __half2 h1 = __floats2half2_rn(l * __logf(a.z + 1e-8f),
                                   l * __logf(a.w + 1e-8f));
    union { __half2 h[2]; uint2 u; } pk;
    pk.h[0] = h0; pk.h[1] = h1;
    ((uint2*)llogA)[(size_t)row * 256 + tid] = pk.u;
    return;
  }
  __shared__ float Wl[64 * 129];     // W transposed [d][f]; reused as Zl[32][130]
  __shared__ float4 xr4[32 * 16];    // x_red tile [row][dq]
  int rb = bk * 32;                  // flat row base (b*1024 + c0)

  // stage W transposed (L2-hot after first blocks)
#pragma unroll
  for (int k = 0; k < 32; ++k) {
    int g = k * 256 + tid;           // g = f*64 + d
    Wl[(g & 63) * 129 + (g >> 6)] = W[g];
  }

  // stream x: contiguous per-wave sweeps (R14 pair form), NT loads.
  // lane l reads offset l of each 1KB step (t = s*4 + (l>>4), dq = l&15).
  {
    int w = tid >> 6, l = tid & 63;
    int tg = l >> 4, dq = l & 15;
#pragma unroll
    for (int p = 0; p < 4; ++p) {
      int rA = w * 8 + p * 2, rBr = rA + 1;
      const f32x4* baseA = (const f32x4*)(X4 + ((size_t)(rb + rA)) * 1024 + l);
      const f32x4* baseB = (const f32x4*)(X4 + ((size_t)(rb + rBr)) * 1024 + l);
      f32x4 aA = {0.f, 0.f, 0.f, 0.f};
      f32x4 aB = {0.f, 0.f, 0.f, 0.f};
#pragma unroll
      for (int s = 0; s < 16; ++s) {
        f32x4 vA = __builtin_nontemporal_load(&baseA[s * 64]);
        f32x4 vB = __builtin_nontemporal_load(&baseB[s * 64]);
        aA[0] += vA[0]; aA[1] += vA[1]; aA[2] += vA[2]; aA[3] += vA[3];
        aB[0] += vB[0]; aB[1] += vB[1]; aB[2] += vB[2]; aB[3] += vB[3];
      }
      // reduce across the 4 t-groups (lanes xor 16, 32)
      float4 fA = make_float4(aA[0], aA[1], aA[2], aA[3]);
      float4 fB = make_float4(aB[0], aB[1], aB[2], aB[3]);
      fA.x += __shfl_xor(fA.x, 16); fA.y += __shfl_xor(fA.y, 16);
      fA.z += __shfl_xor(fA.z, 16); fA.w += __shfl_xor(fA.w, 16);
      fA.x += __shfl_xor(fA.x, 32); fA.y += __shfl_xor(fA.y, 32);
      fA.z += __shfl_xor(fA.z, 32); fA.w += __shfl_xor(fA.w, 32);
      fB.x += __shfl_xor(fB.x, 16); fB.y += __shfl_xor(fB.y, 16);
      fB.z += __shfl_xor(fB.z, 16); fB.w += __shfl_xor(fB.w, 16);
      fB.x += __shfl_xor(fB.x, 32); fB.y += __shfl_xor(fB.y, 32);
      fB.z += __shfl_xor(fB.z, 32); fB.w += __shfl_xor(fB.w, 32);
      if (tg == 0) {
        const float inv = 1.0f / 64.0f;
        fA.x *= inv; fA.y *= inv; fA.z *= inv; fA.w *= inv;
        fB.x *= inv; fB.y *= inv; fB.z *= inv; fB.w *= inv;
        xr4[rA * 16 + dq] = fA;
        xr4[rBr * 16 + dq] = fB;
      }
    }
  }
  __syncthreads();

  // partial x_glob: sum of this block's 32 xr rows
  if (tid < 16) {
    float4 p = make_float4(0.f, 0.f, 0.f, 0.f);
#pragma unroll
    for (int r = 0; r < 32; ++r) {
      float4 v = xr4[r * 16 + tid];
      p.x += v.x; p.y += v.y; p.z += v.z; p.w += v.w;
    }
    pXG4[bk * 16 + tid] = p;
  }

  // GEMV: Z[row][f] = b[f] + xr[row,:] . W[f,:]
  int f = tid & 127, rg = tid >> 7;
  float wreg[64];
#pragma unroll
  for (int d = 0; d < 64; ++d) wreg[d] = Wl[d * 129 + f];
  float bias = bproj[f];
  float acc[16];
#pragma unroll
  for (int r = 0; r < 16; ++r) acc[r] = bias;
#pragma unroll
  for (int r = 0; r < 16; ++r) {
    int row = rg * 16 + r;
#pragma unroll
    for (int dq = 0; dq < 16; ++dq) {
      float4 xv = xr4[row * 16 + dq];
      acc[r] = fmaf(wreg[dq * 4 + 0], xv.x, acc[r]);
      acc[r] = fmaf(wreg[dq * 4 + 1], xv.y, acc[r]);
      acc[r] = fmaf(wreg[dq * 4 + 2], xv.z, acc[r]);
      acc[r] = fmaf(wreg[dq * 4 + 3], xv.w, acc[r]);
    }
  }
  // bf16 k-major chunks: Zk[b][c/8][f][c&7]
  int b = rb >> 10;
  int cbase = (rb & 1023) + rg * 16;
#pragma unroll
  for (int k2 = 0; k2 < 2; ++k2) {
    unsigned w0 = f2bf(acc[k2 * 8 + 0]) | (f2bf(acc[k2 * 8 + 1]) << 16);
    unsigned w1 = f2bf(acc[k2 * 8 + 2]) | (f2bf(acc[k2 * 8 + 3]) << 16);
    unsigned w2 = f2bf(acc[k2 * 8 + 4]) | (f2bf(acc[k2 * 8 + 5]) << 16);
    unsigned w3 = f2bf(acc[k2 * 8 + 6]) | (f2bf(acc[k2 * 8 + 7]) << 16);
    size_t chunk = ((size_t)b * 128 + ((cbase >> 3) + k2)) * 128 + f;
    Zk[chunk] = make_uint4(w0, w1, w2, w3);
  }
  // ei/ej tail: stage fp32 Z tile into LDS (reuse Wl), reduce
  __syncthreads();                   // all Wl/xr4 reads done
  float* Zl = Wl;                    // [32][130]
#pragma unroll
  for (int r = 0; r < 16; ++r)
    Zl[(rg * 16 + r) * 130 + f] = acc[r];
  __syncthreads();
  int row = tid >> 3, g = tid & 7;   // 32 rows x 8 groups of 16 f
  float si = 0.f, sj = 0.f;
#pragma unroll
  for (int u = 0; u < 16; ++u) {
    float z = Zl[row * 130 + g * 16 + u];
    si = fmaf(z, att[g * 16 + u], si);
    sj = fmaf(z, att[128 + g * 16 + u], sj);
  }
  si += __shfl_xor(si, 1); sj += __shfl_xor(sj, 1);
  si += __shfl_xor(si, 2); sj += __shfl_xor(sj, 2);
  si += __shfl_xor(si, 4); sj += __shfl_xor(sj, 4);
  if (g == 0) { ei[rb + row] = si; ej[rb + row] = sj; }
}

// ================= K2: flash softmax @ Z via MFMA (R12-exact) =================
__global__ __launch_bounds__(64) void k_main(const uint4* __restrict__ Zk,
    const __half* __restrict__ llogA, const float* __restrict__ ei,
    const float* __restrict__ ej, const float* __restrict__ pXG,
    const float* __restrict__ Ws1, const float* __restrict__ bs1,
    const float* __restrict__ Ws2, const float* __restrict__ bs2,
    const float* __restrict__ Wc1, const float* __restrict__ bc1,
    const float* __restrict__ Wc2, const float* __restrict__ bc2,
    const float* __restrict__ att,
    float* __restrict__ hout, float* __restrict__ sout) {
  int bid = blockIdx.x;
  int b = ((bid & 7) << 2) | ((bid >> 3) & 3);
  int rowgrp = bid >> 5;               // 0..63
  int i0 = rowgrp * 16;
  int lane = threadIdx.x;
  int lg = lane >> 4, ln = lane & 15;

  // ---- pre-phase: x_glob -> s -> c -> ec (shfl-based, wave-local) ----
  float ecb;
  {
    float xg = 0.f;
    const float* pb = pXG + (size_t)b * 32 * 64;
#pragma unroll 8
    for (int p = 0; p < 32; ++p) xg += pb[p * 64 + lane];
    xg *= (1.0f / 1024.0f);
    const float* w1 = Ws1 + lane * 64;
    float h = bs1[lane];
#pragma unroll 16
    for (int d = 0; d < 64; ++d) h = fmaf(__shfl(xg, d), w1[d], h);
    h = fmaxf(h, 0.f);
    int ln5 = lane < 5 ? lane : 4;
    const float* w2 = Ws2 + ln5 * 64;
    float l = bs2[ln5];
#pragma unroll 16
    for (int k = 0; k < 64; ++k) l = fmaf(__shfl(h, k), w2[k], l);
    float s0 = __shfl(l, 0), s1 = __shfl(l, 1), s2 = __shfl(l, 2),
          s3 = __shfl(l, 3), s4 = __shfl(l, 4);
    float m = fmaxf(fmaxf(fmaxf(s0, s1), fmaxf(s2, s3)), s4);
    float e0 = __expf(s0 - m), e1 = __expf(s1 - m), e2 = __expf(s2 - m),
          e3 = __expf(s3 - m), e4 = __expf(s4 - m);
    float inv = 1.0f / (e0 + e1 + e2 + e3 + e4);
    s0 = e0 * inv; s1 = e1 * inv; s2 = e2 * inv; s3 = e3 * inv; s4 = e4 * inv;
    if (rowgrp == 0 && lane == 0) {
      sout[b * 5 + 0] = s0; sout[b * 5 + 1] = s1; sout[b * 5 + 2] = s2;
      sout[b * 5 + 3] = s3; sout[b * 5 + 4] = s4;
    }
    const float* wc1 = Wc1 + lane * 5;
    float cv = bc1[lane];
    cv = fmaf(s0, wc1[0], cv); cv = fmaf(s1, wc1[1], cv);
    cv = fmaf(s2, wc1[2], cv); cv = fmaf(s3, wc1[3], cv);
    cv = fmaf(s4, wc1[4], cv);
    cv = fmaxf(cv, 0.f);
    const float* wc2 = Wc2 + lane * 64;
    float c2 = bc2[lane];
#pragma unroll 16
    for (int k = 0; k < 64; ++k) c2 = fmaf(__shfl(cv, k), wc2[k], c2);
    float v = c2 * att[256 + lane];
#pragma unroll
    for (int o = 32; o; o >>= 1) v += __shfl_xor(v, o);
    ecb = v;
  }

  // ---- flash loop ----
  int i_gl = i0 + ln;
  float eir = ei[b * 1024 + i_gl];
  const uint4*  lrowH = (const uint4*)(llogA + (size_t)i_gl * 1024); // 8 halves/chunk
  const float4* ejr4  = (const float4*)(ej + b * 1024);
  const uint4*  ZkB   = Zk + (size_t)b * 128 * 128;

  float m_run = -1e30f, s_run = 0.0f;
  f32x4 acc[8];
#pragma unroll
  for (int q = 0; q < 8; ++q) { f32x4 z = {0.f, 0.f, 0.f, 0.f}; acc[q] = z; }

  for (int jt = 0; jt < 16; ++jt) {
    int j0 = jt * 64;
    uint4 bz[2][8];
#pragma unroll
    for (int ks = 0; ks < 2; ++ks)
#pragma unroll
      for (int fb = 0; fb < 8; ++fb)
        bz[ks][fb] = ZkB[(size_t)((j0 >> 3) + ks * 4 + lg) * 128 + fb * 16 + ln];
    float tv[16];
    float tm = -1e30f;
#pragma unroll
    for (int ks = 0; ks < 2; ++ks) {
      int jb = (j0 + ks * 32 + lg * 8) >> 2;      // float4 index (ej)
      float4 e0 = ejr4[jb], e1 = ejr4[jb + 1];
      union { uint4 u; __half2 h[4]; } lu;
      lu.u = lrowH[jb >> 1];                      // 8 halves = same 8 j's
      float2 f0 = __half22float2(lu.h[0]);
      float2 f1 = __half22float2(lu.h[1]);
      float2 f2 = __half22float2(lu.h[2]);
      float2 f3 = __half22float2(lu.h[3]);
      float eq[8] = {e0.x, e0.y, e0.z, e0.w, e1.x, e1.y, e1.z, e1.w};
      float lq[8] = {f0.x, f0.y, f1.x, f1.y, f2.x, f2.y, f3.x, f3.y};
#pragma unroll
      for (int u = 0; u < 8; ++u) {
        float t = eir + eq[u] + ecb;
        t = t > 0.0f ? t : 0.2f * t;          // leaky_relu(0.2)
        t += lq[u];                            // + lam*log(A+eps) (fp16)
        tv[ks * 8 + u] = t;
        tm = fmaxf(tm, t);
      }
    }
    tm = fmaxf(tm, __shfl_xor(tm, 16));
    tm = fmaxf(tm, __shfl_xor(tm, 32));
    float newm = fmaxf(m_run, tm);
    float scale = __expf(m_run - newm);
    float ts = 0.0f;
    unsigned pw[8];
#pragma unroll
    for (int q = 0; q < 8; ++q) {
      float p0 = __expf(tv[2 * q] - newm);
      float p1 = __expf(tv[2 * q + 1] - newm);
      ts += p0 + p1;
      pw[q] = f2bf(p0) | (f2bf(p1) << 16);
    }
    ts += __shfl_xor(ts, 16);
    ts += __shfl_xor(ts, 32);
    s_run = s_run * scale + ts;
    m_run = newm;
#pragma unroll
    for (int q = 0; q < 8; ++q) acc[q] *= scale;
    union { unsigned u[4]; bf16x8 v; } c0, c1;
#pragma unroll
    for (int q = 0; q < 4; ++q) { c0.u[q] = pw[q]; c1.u[q] = pw[4 + q]; }
#pragma unroll
    for (int fb = 0; fb < 8; ++fb)
      acc[fb] = __builtin_amdgcn_mfma_f32_16x16x32_bf16(c0.v, *(bf16x8*)&bz[0][fb], acc[fb], 0, 0, 0);
#pragma unroll
    for (int fb = 0; fb < 8; ++fb)
      acc[fb] = __builtin_amdgcn_mfma_f32_16x16x32_bf16(c1.v, *(bf16x8*)&bz[1][fb], acc[fb], 0, 0, 0);
  }

  // epilogue: normalize by D-row 1/s, write out
  float invs = 1.0f / s_run;
  float inv_m[4];
#pragma unroll
  for (int r = 0; r < 4; ++r) inv_m[r] = __shfl(invs, lg * 4 + r);
  float* hb = hout + ((size_t)b * 1024 + i0 + lg * 4) * 128 + ln;
#pragma unroll
  for (int fb = 0; fb < 8; ++fb) {
#pragma unroll
    for (int r = 0; r < 4; ++r)
      hb[(size_t)r * 128 + fb * 16] = acc[fb][r] * inv_m[r];
  }
}

extern "C" void kernel_launch(void* const* d_in, const int* in_sizes, int n_in,
                              void* d_out, int out_size, void* d_ws, size_t ws_size,
                              hipStream_t stream) {
  const float* x     = (const float*)d_in[0];
  const float* Ainit = (const float*)d_in[1];
  const float* Wproj = (const float*)d_in[2];
  const float* bproj = (const float*)d_in[3];
  const float* Ws1   = (const float*)d_in[4];
  const float* bs1   = (const float*)d_in[5];
  const float* Ws2   = (const float*)d_in[6];
  const float* bs2   = (const float*)d_in[7];
  const float* Wc1   = (const float*)d_in[8];
  const float* bc1   = (const float*)d_in[9];
  const float* Wc2   = (const float*)d_in[10];
  const float* bc2   = (const float*)d_in[11];
  const float* att   = (const float*)d_in[12];
  const float* lam   = (const float*)d_in[13];

  float* ws    = (float*)d_ws;
  __half* llogA = (__half*)(ws + LOGA_OFF);
  float* ei    = ws + EI_OFF;
  float* ej    = ws + EJ_OFF;
  float* pXG   = ws + PXG_OFF;
  uint4* Zk    = (uint4*)(ws + ZK_OFF);

  float* hout = (float*)d_out;                  // (32,1024,128)
  float* sout = hout + (size_t)32 * 1024 * 128; // (32,5)

  hipLaunchKernelGGL(k_fuse1, dim3(2048), dim3(256), 0, stream,
                     (const float4*)x, Ainit, lam, Wproj, bproj, att,
                     Zk, ei, ej, (float4*)pXG, llogA);
  hipLaunchKernelGGL(k_main,  dim3(2048), dim3(64),  0, stream,
                     Zk, llogA, ei, ej, pXG,
                     Ws1, bs1, Ws2, bs2, Wc1, bc1, Wc2, bc2, att,
                     hout, sout);
}